// Round 5
// baseline (1098.741 us; speedup 1.0000x reference)
//
#include <hip/hip_runtime.h>

// ---- problem constants (match reference) ----
#define NTOK   16384      // B*T
#define DMODEL 1024
#define FFF    4096
#define NEXP   8
#define CAP    2560       // int(1.25 * NTOK / NEXP)
#define NASSIGN (NTOK*2)  // top-2

typedef __bf16 bf16x8 __attribute__((ext_vector_type(8)));
typedef float  f32x4  __attribute__((ext_vector_type(4)));
typedef unsigned short u16x8 __attribute__((ext_vector_type(8)));

__device__ __forceinline__ unsigned short f2bf(float f) {
    unsigned int u = __float_as_uint(f);
    u = u + 0x7FFFu + ((u >> 16) & 1u);   // RNE
    return (unsigned short)(u >> 16);
}
__device__ __forceinline__ float bf2f(unsigned short s) {
    return __uint_as_float(((unsigned int)s) << 16);
}

// ======== router: one wave per token. fp32 logits -> softmax -> top2 ========
// Also writes the bf16 copy of x (xb16) so GEMM1 can gather directly
// (dispatch_kernel is eliminated). topi is published with AGENT-scope atomic
// stores so the in-kernel scan (last router block) can read it coherently
// across XCDs (per-XCD L2s are non-coherent).
__device__ void router_body(int rb, const float* __restrict__ x,
                            const float* __restrict__ wr,
                            const float* __restrict__ br,
                            int* __restrict__ topi,
                            float* __restrict__ topv,
                            unsigned short* __restrict__ xb16) {
    int t    = rb * 4 + (threadIdx.x >> 6);
    int lane = threadIdx.x & 63;
    const float4* xr4 = reinterpret_cast<const float4*>(x + (size_t)t * DMODEL);
    ushort4* xw = reinterpret_cast<ushort4*>(xb16 + (size_t)t * DMODEL);
    float a[8] = {0.f,0.f,0.f,0.f,0.f,0.f,0.f,0.f};
    #pragma unroll
    for (int i = lane; i < DMODEL/4; i += 64) {
        float4 xv = xr4[i];
        ushort4 o;
        o.x = f2bf(xv.x); o.y = f2bf(xv.y); o.z = f2bf(xv.z); o.w = f2bf(xv.w);
        xw[i] = o;
        const float* w = wr + i * 32;
        #pragma unroll
        for (int e = 0; e < 8; e++) a[e] = fmaf(xv.x, w[e],      a[e]);
        #pragma unroll
        for (int e = 0; e < 8; e++) a[e] = fmaf(xv.y, w[8 + e],  a[e]);
        #pragma unroll
        for (int e = 0; e < 8; e++) a[e] = fmaf(xv.z, w[16 + e], a[e]);
        #pragma unroll
        for (int e = 0; e < 8; e++) a[e] = fmaf(xv.w, w[24 + e], a[e]);
    }
    #pragma unroll
    for (int off = 32; off > 0; off >>= 1) {
        #pragma unroll
        for (int e = 0; e < 8; e++) a[e] += __shfl_xor(a[e], off, 64);
    }
    if (lane == 0) {
        float l[8], g[8];
        float mx = -1e30f;
        #pragma unroll
        for (int e = 0; e < 8; e++) { l[e] = a[e] + br[e]; mx = fmaxf(mx, l[e]); }
        float s = 0.f;
        #pragma unroll
        for (int e = 0; e < 8; e++) { g[e] = expf(l[e] - mx); s += g[e]; }
        float inv = 1.f / s;
        #pragma unroll
        for (int e = 0; e < 8; e++) g[e] *= inv;
        float v1 = -1.f, v2 = -1.f; int i1 = 0, i2 = 0;
        #pragma unroll
        for (int e = 0; e < 8; e++) {
            float v = g[e];
            if (v > v1)      { v2 = v1; i2 = i1; v1 = v; i1 = e; }
            else if (v > v2) { v2 = v; i2 = e; }
        }
        __hip_atomic_store(topi + t*2,     i1, __ATOMIC_RELAXED, __HIP_MEMORY_SCOPE_AGENT);
        __hip_atomic_store(topi + t*2 + 1, i2, __ATOMIC_RELAXED, __HIP_MEMORY_SCOPE_AGENT);
        topv[t*2]   = v1; topv[t*2+1] = v2;
    }
}

// ------- scan body: arrival-order positions per expert (256 threads) -------
// Runs inline in the LAST router block; topi reads are agent-scope (bypass
// the reader XCD's possibly-stale L2). Outputs (pos/slot_tok/kept) are plain
// stores — consumed only by later kernels (boundary-coherent).
__device__ void scan_body(const int* __restrict__ topi,
                          int* __restrict__ pos,
                          int* __restrict__ slot_tok,
                          int* __restrict__ kept) {
    const int APT = NASSIGN / 256;
    int tid = threadIdx.x, lane = tid & 63, w = tid >> 6;
    int base = tid * APT;
    auto ld = [&](int idx) {
        return __hip_atomic_load(topi + idx, __ATOMIC_RELAXED, __HIP_MEMORY_SCOPE_AGENT);
    };
    int c[8] = {0,0,0,0,0,0,0,0};
    for (int i = 0; i < APT/4; i++) {
        int vx = ld(base + i*4 + 0), vy = ld(base + i*4 + 1);
        int vz = ld(base + i*4 + 2), vw = ld(base + i*4 + 3);
        #pragma unroll
        for (int q = 0; q < 8; q++)
            c[q] += (vx == q) + (vy == q) + (vz == q) + (vw == q);
    }
    int excl[8], wtot[8];
    #pragma unroll
    for (int e = 0; e < 8; e++) {
        int s = c[e];
        for (int off = 1; off < 64; off <<= 1) {
            int n = __shfl_up(s, off, 64);
            if (lane >= off) s += n;
        }
        excl[e] = s - c[e];
        wtot[e] = __shfl(s, 63, 64);
    }
    __shared__ int woff[4][8];
    if (lane == 0) {
        #pragma unroll
        for (int e = 0; e < 8; e++) woff[w][e] = wtot[e];
    }
    __syncthreads();
    if (tid == 0) {
        for (int e = 0; e < 8; e++) {
            int run = 0;
            for (int ww = 0; ww < 4; ww++) { int t0 = woff[ww][e]; woff[ww][e] = run; run += t0; }
            kept[e] = run < CAP ? run : CAP;
        }
    }
    __syncthreads();
    int run[8];
    #pragma unroll
    for (int e = 0; e < 8; e++) run[e] = woff[w][e] + excl[e];
    for (int i = 0; i < APT/4; i++) {
        int ev[4];
        ev[0] = ld(base + i*4 + 0); ev[1] = ld(base + i*4 + 1);
        ev[2] = ld(base + i*4 + 2); ev[3] = ld(base + i*4 + 3);
        #pragma unroll
        for (int u = 0; u < 4; u++) {
            int a = base + i*4 + u;
            int e = ev[u];
            int p = 0;
            #pragma unroll
            for (int q = 0; q < 8; q++) if (e == q) { p = run[q]; run[q] = p + 1; }
            pos[a] = p;
            if (p < CAP) slot_tok[(size_t)e * CAP + p] = a >> 1;
        }
    }
}

// transpose fp32 [R][C] tile (r0,c0) -> bf16 [C][R]; 64x64, pad 65 (2-way max)
__device__ void transpose_body(const float* __restrict__ src,
                               unsigned short* __restrict__ dst,
                               int R, int C, int r0, int c0) {
    __shared__ float tile[64 * 65];
    int t = threadIdx.x;
    int lr4 = (t & 15) * 4;
    #pragma unroll
    for (int s = 0; s < 4; s++) {
        int r = (t >> 4) + s * 16;
        float4 v = *reinterpret_cast<const float4*>(&src[(size_t)(r0 + r) * C + c0 + lr4]);
        float* tr = &tile[r * 65 + lr4];
        tr[0] = v.x; tr[1] = v.y; tr[2] = v.z; tr[3] = v.w;
    }
    __syncthreads();
    int j = t & 7;
    int ccb = t >> 3;
    #pragma unroll
    for (int s = 0; s < 2; s++) {
        int cc = ccb + s * 32;
        u16x8 o;
        #pragma unroll
        for (int k = 0; k < 8; k++) o[k] = f2bf(tile[(j * 8 + k) * 65 + cc]);
        *reinterpret_cast<u16x8*>(&dst[(size_t)(c0 + cc) * R + r0 + j * 8]) = o;
    }
}

// ==== fused prologue: router (+xb16, +inline scan in last router block) ====
// ==== + w1/w2 transposes (independent -> scan hides under them)         ====
__global__ void prologue_kernel(const float* __restrict__ x,
                                const float* __restrict__ wr,
                                const float* __restrict__ br,
                                const float* __restrict__ w1,
                                const float* __restrict__ w2,
                                int* __restrict__ topi,
                                float* __restrict__ topv,
                                unsigned short* __restrict__ w1t,
                                unsigned short* __restrict__ w2t,
                                unsigned short* __restrict__ xb16,
                                int* __restrict__ ctr,
                                int* __restrict__ pos,
                                int* __restrict__ slot_tok,
                                int* __restrict__ kept) {
    int id = blockIdx.x;
    if (id < NTOK/4) {
        router_body(id, x, wr, br, topi, topv, xb16);
        __syncthreads();
        __shared__ int trig;
        if (threadIdx.x == 0) {
            __threadfence();                       // release our topi stores
            int old = atomicAdd(ctr, 1);           // device-scope by default
            trig = (old == NTOK/4 - 1) ? 1 : 0;
        }
        __syncthreads();
        if (trig) {
            __threadfence();                       // acquire
            scan_body(topi, pos, slot_tok, kept);
        }
    } else if (id < NTOK/4 + 8192) {
        int q = id - NTOK/4;
        int e = q >> 10, t = q & 1023;
        int bx = t & 63, by = t >> 6;
        transpose_body(w1 + (size_t)e * DMODEL * FFF,
                       w1t + (size_t)e * DMODEL * FFF,
                       DMODEL, FFF, by * 64, bx * 64);
    } else {
        int q = id - NTOK/4 - 8192;
        int e = q >> 10, t = q & 1023;
        int bx = t & 15, by = t >> 4;
        transpose_body(w2 + (size_t)e * DMODEL * FFF,
                       w2t + (size_t)e * DMODEL * FFF,
                       FFF, DMODEL, by * 64, bx * 64);
    }
}

// ------------- GEMM (proven 128² structure): C = A * Bt^T + bias -------------
// GATHER=1: A rows are gathered through slot_tok from xb16 [NTOK][D] —
// per-lane GLOBAL source addresses are legal for global_load_lds (only the
// LDS dest must be wave-uniform). Token ids preloaded once per lane; &(NTOK-1)
// keeps stale/garbage slots in-bounds (xb16 is fully rewritten each iter, so
// any in-bounds row is finite; dropped slots are multiplied by w=0 later).
template<int GELU, int GATHER>
__global__ __launch_bounds__(256, 2)
void gemm_bt(const unsigned short* __restrict__ A,
             const unsigned short* __restrict__ Bt,
             const float* __restrict__ bias,
             unsigned short* __restrict__ C,
             int M, int N, int K,
             const int* __restrict__ slot_tok) {
    constexpr int BM = 128, BN = 128, BK = 64;
    __shared__ unsigned short As[BM * 64];
    __shared__ unsigned short Bs[BN * 64];
    const int e = blockIdx.z;
    const int gx = N / BN, gy = M / BM;
    const int nc = gx < 8 ? gx : 8;          // n-chunk width
    int id = blockIdx.x;
    const int per_chunk = nc * gy;
    const int chunk = id / per_chunk;
    const int r = id - chunk * per_chunk;
    const int bn = chunk * nc + (r % nc);
    const int bm = r / nc;

    const unsigned short* Ab = A  + (size_t)e * M * K + (size_t)bm * BM * K;
    const unsigned short* Bb = Bt + (size_t)e * N * K + (size_t)bn * BN * K;
    const float* bp = bias + (size_t)e * N;
    const int tid  = threadIdx.x;
    const int lane = tid & 63;
    const int wv   = tid >> 6;
    const int wm   = (wv >> 1) * 64;
    const int wn   = (wv & 1) * 64;
    const int lr   = lane & 15;
    const int quad = lane >> 4;
    const int srow   = lane >> 3;
    const int schunk = (lane & 7) ^ srow;
    const int swiz   = lr & 7;

    // per-lane A source row bases (gather or direct)
    const unsigned short* asrc[4];
    #pragma unroll
    for (int s = 0; s < 4; s++) {
        int row = (wv * 4 + s) * 8 + srow;
        if (GATHER) {
            int tok = slot_tok[(size_t)e * CAP + bm * BM + row] & (NTOK - 1);
            asrc[s] = A + (size_t)tok * K + schunk * 8;
        } else {
            asrc[s] = Ab + (size_t)row * K + schunk * 8;
        }
    }

    f32x4 acc[4][4] = {};

    for (int kb = 0; kb < K; kb += BK) {
        #pragma unroll
        for (int s = 0; s < 4; s++) {
            int q = wv * 4 + s;
            int row = q * 8 + srow;
            __builtin_amdgcn_global_load_lds(
                (const __attribute__((address_space(1))) unsigned int*)(asrc[s] + kb),
                (__attribute__((address_space(3))) unsigned int*)(As + q * 512),
                16, 0, 0);
            __builtin_amdgcn_global_load_lds(
                (const __attribute__((address_space(1))) unsigned int*)(Bb + (size_t)row * K + kb + schunk * 8),
                (__attribute__((address_space(3))) unsigned int*)(Bs + q * 512),
                16, 0, 0);
        }
        __syncthreads();
        #pragma unroll
        for (int kk = 0; kk < BK; kk += 32) {
            bf16x8 af[4], bfr[4];
            const int sc = ((kk >> 3) + quad) ^ swiz;
            #pragma unroll
            for (int i = 0; i < 4; i++)
                af[i] = *reinterpret_cast<const bf16x8*>(&As[(wm + i*16 + lr) * 64 + sc * 8]);
            #pragma unroll
            for (int j = 0; j < 4; j++)
                bfr[j] = *reinterpret_cast<const bf16x8*>(&Bs[(wn + j*16 + lr) * 64 + sc * 8]);
            #pragma unroll
            for (int i = 0; i < 4; i++)
                #pragma unroll
                for (int j = 0; j < 4; j++)
                    acc[i][j] = __builtin_amdgcn_mfma_f32_16x16x32_bf16(af[i], bfr[j], acc[i][j], 0, 0, 0);
        }
        __syncthreads();
    }

    size_t cbase = (size_t)e * M * N + (size_t)bm * BM * N + (size_t)bn * BN;
    float bv[4];
    #pragma unroll
    for (int j = 0; j < 4; j++) bv[j] = bp[bn * BN + wn + j * 16 + lr];
    #pragma unroll
    for (int i = 0; i < 4; i++) {
        #pragma unroll
        for (int rr = 0; rr < 4; rr++) {
            int row = wm + i * 16 + quad * 4 + rr;
            #pragma unroll
            for (int j = 0; j < 4; j++) {
                int col = wn + j * 16 + lr;
                float v = acc[i][j][rr] + bv[j];
                if (GELU) v = 0.5f * v * (1.f + erff(v * 0.70710678118654752440f));
                C[cbase + (size_t)row * N + col] = f2bf(v);
            }
        }
    }
}

// ------------- combine: weighted sum of expert outputs, normalize -------------
__global__ void combine_kernel(const int* __restrict__ topi,
                               const float* __restrict__ topv,
                               const int* __restrict__ pos,
                               const unsigned short* __restrict__ out2,
                               float* __restrict__ y) {
    int t    = blockIdx.x * 4 + (threadIdx.x >> 6);
    int lane = threadIdx.x & 63;
    int e0 = topi[t*2],   e1 = topi[t*2+1];
    float g0 = topv[t*2], g1 = topv[t*2+1];
    int p0 = pos[t*2],    p1 = pos[t*2+1];
    float w0 = (p0 < CAP) ? g0 : 0.f;
    float w1 = (p1 < CAP) ? g1 : 0.f;
    float wsum = w0 + w1;
    float scale = (wsum > 0.f) ? 1.f / fmaxf(wsum, 1e-6f) : 0.f;
    int q0 = p0 < CAP ? p0 : CAP - 1;
    int q1 = p1 < CAP ? p1 : CAP - 1;
    const ushort4* o0 = reinterpret_cast<const ushort4*>(out2 + ((size_t)e0 * CAP + q0) * DMODEL);
    const ushort4* o1 = reinterpret_cast<const ushort4*>(out2 + ((size_t)e1 * CAP + q1) * DMODEL);
    float4* dst = reinterpret_cast<float4*>(y + (size_t)t * DMODEL);
    #pragma unroll
    for (int i = lane; i < DMODEL/4; i += 64) {
        ushort4 a = o0[i], b = o1[i];
        float4 r;
        r.x = (w0 * bf2f(a.x) + w1 * bf2f(b.x)) * scale;
        r.y = (w0 * bf2f(a.y) + w1 * bf2f(b.y)) * scale;
        r.z = (w0 * bf2f(a.z) + w1 * bf2f(b.z)) * scale;
        r.w = (w0 * bf2f(a.w) + w1 * bf2f(b.w)) * scale;
        dst[i] = r;
    }
}

extern "C" void kernel_launch(void* const* d_in, const int* in_sizes, int n_in,
                              void* d_out, int out_size, void* d_ws, size_t ws_size,
                              hipStream_t stream) {
    (void)in_sizes; (void)n_in; (void)out_size; (void)ws_size;
    const float* x        = (const float*)d_in[0];
    const float* w_router = (const float*)d_in[1];
    const float* b_router = (const float*)d_in[2];
    const float* w1       = (const float*)d_in[3];
    const float* b1       = (const float*)d_in[4];
    const float* w2       = (const float*)d_in[5];
    const float* b2       = (const float*)d_in[6];
    float* y = (float*)d_out;

    char* ws = (char*)d_ws;
    size_t off = 0;
    auto alloc = [&](size_t n) { char* p = ws + off; off = (off + n + 255) & ~(size_t)255; return p; };
    int*   topi     = (int*)  alloc((size_t)NASSIGN * 4);
    float* topv     = (float*)alloc((size_t)NASSIGN * 4);
    int*   pos      = (int*)  alloc((size_t)NASSIGN * 4);
    int*   slot_tok = (int*)  alloc((size_t)NEXP * CAP * 4);
    int*   kept     = (int*)  alloc(8 * 4);
    int*   ctr      = (int*)  alloc(4);
    unsigned short* w1t  = (unsigned short*)alloc((size_t)NEXP * DMODEL * FFF * 2);
    unsigned short* w2t  = (unsigned short*)alloc((size_t)NEXP * DMODEL * FFF * 2);
    unsigned short* xb16 = (unsigned short*)alloc((size_t)NTOK * DMODEL * 2);
    unsigned short* h    = (unsigned short*)alloc((size_t)NEXP * CAP * FFF * 2);
    unsigned short* out2 = w1t;  // alias: w1t is dead after GEMM1

    hipMemsetAsync(ctr, 0, 4, stream);
    prologue_kernel<<<NTOK/4 + 16384, 256, 0, stream>>>(
        x, w_router, b_router, w1, w2, topi, topv, w1t, w2t,
        xb16, ctr, pos, slot_tok, kept);
    gemm_bt<1, 1><<<dim3((FFF/128)*(CAP/128), 1, NEXP), 256, 0, stream>>>(
        xb16, w1t, b1, h, CAP, FFF, DMODEL, slot_tok);
    gemm_bt<0, 0><<<dim3((DMODEL/128)*(CAP/128), 1, NEXP), 256, 0, stream>>>(
        h, w2t, b2, out2, CAP, DMODEL, FFF, nullptr);
    combine_kernel<<<NTOK/4, 256, 0, stream>>>(topi, topv, pos, out2, y);
}

// Round 7
// 914.976 us; speedup vs baseline: 1.2008x; 1.2008x over previous
//
#include <hip/hip_runtime.h>

// ---- problem constants (match reference) ----
#define NTOK   16384      // B*T
#define DMODEL 1024
#define FFF    4096
#define NEXP   8
#define CAP    2560       // int(1.25 * NTOK / NEXP)
#define NASSIGN (NTOK*2)  // top-2

typedef __bf16 bf16x8 __attribute__((ext_vector_type(8)));
typedef float  f32x4  __attribute__((ext_vector_type(4)));
typedef unsigned short u16x8 __attribute__((ext_vector_type(8)));

__device__ __forceinline__ unsigned short f2bf(float f) {
    unsigned int u = __float_as_uint(f);
    u = u + 0x7FFFu + ((u >> 16) & 1u);   // RNE
    return (unsigned short)(u >> 16);
}
__device__ __forceinline__ float bf2f(unsigned short s) {
    return __uint_as_float(((unsigned int)s) << 16);
}

// ======== fused prologue: router (blocks 0..4095) + w1/w2 transpose ========
// router: one wave per token, fp32 logits -> softmax -> top2
__device__ void router_body(int rb, const float* __restrict__ x,
                            const float* __restrict__ wr,
                            const float* __restrict__ br,
                            int* __restrict__ topi,
                            float* __restrict__ topv) {
    int t    = rb * 4 + (threadIdx.x >> 6);
    int lane = threadIdx.x & 63;
    const float4* xr4 = reinterpret_cast<const float4*>(x + (size_t)t * DMODEL);
    float a[8] = {0.f,0.f,0.f,0.f,0.f,0.f,0.f,0.f};
    #pragma unroll
    for (int i = lane; i < DMODEL/4; i += 64) {
        float4 xv = xr4[i];
        const float* w = wr + i * 32;
        #pragma unroll
        for (int e = 0; e < 8; e++) a[e] = fmaf(xv.x, w[e],      a[e]);
        #pragma unroll
        for (int e = 0; e < 8; e++) a[e] = fmaf(xv.y, w[8 + e],  a[e]);
        #pragma unroll
        for (int e = 0; e < 8; e++) a[e] = fmaf(xv.z, w[16 + e], a[e]);
        #pragma unroll
        for (int e = 0; e < 8; e++) a[e] = fmaf(xv.w, w[24 + e], a[e]);
    }
    #pragma unroll
    for (int off = 32; off > 0; off >>= 1) {
        #pragma unroll
        for (int e = 0; e < 8; e++) a[e] += __shfl_xor(a[e], off, 64);
    }
    if (lane == 0) {
        float l[8], g[8];
        float mx = -1e30f;
        #pragma unroll
        for (int e = 0; e < 8; e++) { l[e] = a[e] + br[e]; mx = fmaxf(mx, l[e]); }
        float s = 0.f;
        #pragma unroll
        for (int e = 0; e < 8; e++) { g[e] = expf(l[e] - mx); s += g[e]; }
        float inv = 1.f / s;
        #pragma unroll
        for (int e = 0; e < 8; e++) g[e] *= inv;
        float v1 = -1.f, v2 = -1.f; int i1 = 0, i2 = 0;
        #pragma unroll
        for (int e = 0; e < 8; e++) {
            float v = g[e];
            if (v > v1)      { v2 = v1; i2 = i1; v1 = v; i1 = e; }
            else if (v > v2) { v2 = v; i2 = e; }
        }
        topi[t*2]   = i1; topi[t*2+1] = i2;
        topv[t*2]   = v1; topv[t*2+1] = v2;
    }
}

// 4-tile pipelined transpose: fp32 [R][C] tiles (r0, c0base + it*64),
// it=0..3 -> bf16 [C][R]. T14 issue-early split: the next tile's global
// loads are issued right after the barrier, so their HBM round-trip hides
// under the current tile's LDS-read/convert/store phase. Single LDS buffer,
// canonical 2-barrier pattern (write < bar < read < bar < next write).
__device__ void transpose4_body(const float* __restrict__ src,
                                unsigned short* __restrict__ dst,
                                int R, int C, int r0, int c0base) {
    __shared__ float tile[64 * 65];
    int t = threadIdx.x;
    int lr4   = (t & 15) * 4;
    int rbase = t >> 4;                 // 0..15
    int j     = t & 7;
    int ccb   = t >> 3;

    float4 v[4];
    #pragma unroll
    for (int s = 0; s < 4; s++)
        v[s] = *reinterpret_cast<const float4*>(
            &src[(size_t)(r0 + rbase + s * 16) * C + c0base + lr4]);

    for (int it = 0; it < 4; it++) {
        #pragma unroll
        for (int s = 0; s < 4; s++) {
            float* tr = &tile[(rbase + s * 16) * 65 + lr4];
            tr[0] = v[s].x; tr[1] = v[s].y; tr[2] = v[s].z; tr[3] = v[s].w;
        }
        __syncthreads();
        if (it < 3) {
            int c0n = c0base + (it + 1) * 64;
            #pragma unroll
            for (int s = 0; s < 4; s++)
                v[s] = *reinterpret_cast<const float4*>(
                    &src[(size_t)(r0 + rbase + s * 16) * C + c0n + lr4]);
        }
        int c0 = c0base + it * 64;
        #pragma unroll
        for (int s2 = 0; s2 < 2; s2++) {
            int cc = ccb + s2 * 32;
            u16x8 o;
            #pragma unroll
            for (int k = 0; k < 8; k++) o[k] = f2bf(tile[(j * 8 + k) * 65 + cc]);
            *reinterpret_cast<u16x8*>(&dst[(size_t)(c0 + cc) * R + r0 + j * 8]) = o;
        }
        __syncthreads();
    }
}

__global__ void prologue_kernel(const float* __restrict__ x,
                                const float* __restrict__ wr,
                                const float* __restrict__ br,
                                const float* __restrict__ w1,
                                const float* __restrict__ w2,
                                int* __restrict__ topi,
                                float* __restrict__ topv,
                                unsigned short* __restrict__ w1t,
                                unsigned short* __restrict__ w2t) {
    int id = blockIdx.x;
    if (id < NTOK/4) {
        router_body(id, x, wr, br, topi, topv);
    } else if (id < NTOK/4 + 2048) {
        // w1 [e][D][F] -> w1t [e][F][D]; 256 jobs/expert: by=rem>>4 (16),
        // bxg=rem&15 (16 groups of 4 column-tiles)
        int q = id - NTOK/4;
        int e = q >> 8, rem = q & 255;
        int by = rem >> 4, bxg = rem & 15;
        transpose4_body(w1 + (size_t)e * DMODEL * FFF,
                        w1t + (size_t)e * DMODEL * FFF,
                        DMODEL, FFF, by * 64, bxg * 256);
    } else {
        // w2 [e][F][D] -> w2t [e][D][F]; 256 jobs/expert: by=rem>>2 (64),
        // bxg=rem&3 (4 groups of 4 column-tiles)
        int q = id - NTOK/4 - 2048;
        int e = q >> 8, rem = q & 255;
        int by = rem >> 2, bxg = rem & 3;
        transpose4_body(w2 + (size_t)e * DMODEL * FFF,
                        w2t + (size_t)e * DMODEL * FFF,
                        FFF, DMODEL, by * 64, bxg * 256);
    }
}

// ------- scan: arrival-order positions per expert (single block) -------
__global__ void scan_kernel(const int* __restrict__ topi,
                            int* __restrict__ pos,
                            int* __restrict__ slot_tok,
                            int* __restrict__ kept) {
    const int APT = NASSIGN / 256;
    int tid = threadIdx.x, lane = tid & 63, w = tid >> 6;
    int base = tid * APT;
    const int4* tp = reinterpret_cast<const int4*>(topi + base);
    int c[8] = {0,0,0,0,0,0,0,0};
    for (int i = 0; i < APT/4; i++) {
        int4 v = tp[i];
        #pragma unroll
        for (int q = 0; q < 8; q++)
            c[q] += (v.x == q) + (v.y == q) + (v.z == q) + (v.w == q);
    }
    int excl[8], wtot[8];
    #pragma unroll
    for (int e = 0; e < 8; e++) {
        int s = c[e];
        for (int off = 1; off < 64; off <<= 1) {
            int n = __shfl_up(s, off, 64);
            if (lane >= off) s += n;
        }
        excl[e] = s - c[e];
        wtot[e] = __shfl(s, 63, 64);
    }
    __shared__ int woff[4][8];
    if (lane == 0) {
        #pragma unroll
        for (int e = 0; e < 8; e++) woff[w][e] = wtot[e];
    }
    __syncthreads();
    if (tid == 0) {
        for (int e = 0; e < 8; e++) {
            int run = 0;
            for (int ww = 0; ww < 4; ww++) { int t0 = woff[ww][e]; woff[ww][e] = run; run += t0; }
            kept[e] = run < CAP ? run : CAP;
        }
    }
    __syncthreads();
    int run[8];
    #pragma unroll
    for (int e = 0; e < 8; e++) run[e] = woff[w][e] + excl[e];
    for (int i = 0; i < APT/4; i++) {
        int4 v = tp[i];
        int ev[4] = {v.x, v.y, v.z, v.w};
        #pragma unroll
        for (int u = 0; u < 4; u++) {
            int a = base + i*4 + u;
            int e = ev[u];
            int p = 0;
            #pragma unroll
            for (int q = 0; q < 8; q++) if (e == q) { p = run[q]; run[q] = p + 1; }
            pos[a] = p;
            if (p < CAP) slot_tok[(size_t)e * CAP + p] = a >> 1;
        }
    }
}

// ------------- dispatch: gather kept tokens -> bf16 [E][CAP][D] -------------
__global__ void dispatch_kernel(const float* __restrict__ x,
                                const int* __restrict__ slot_tok,
                                const int* __restrict__ kept,
                                unsigned short* __restrict__ xb) {
    int row  = blockIdx.x * 4 + (threadIdx.x >> 6);
    int lane = threadIdx.x & 63;
    int e = row / CAP;
    int p = row - e * CAP;
    if (p >= kept[e]) return;           // wave-uniform
    int t = slot_tok[row];
    const float4* src = reinterpret_cast<const float4*>(x + (size_t)t * DMODEL);
    ushort4* dst = reinterpret_cast<ushort4*>(xb + (size_t)row * DMODEL);
    #pragma unroll
    for (int i = lane; i < DMODEL/4; i += 64) {
        float4 v = src[i];
        ushort4 o;
        o.x = f2bf(v.x); o.y = f2bf(v.y); o.z = f2bf(v.z); o.w = f2bf(v.w);
        dst[i] = o;
    }
}

// ------------- GEMM: C[e][M][N] = A[e][M][K] * Bt[e][N][K]^T + bias -------------
// global_load_lds width=16, XOR chunk swizzle. Block order: per expert, N in
// chunks of 8 tiles with N fastest -> each XCD pins one B-tile in its L2 while
// A streams (L3-resident). grid = dim3(gx*gy, 1, NEXP).
template<int GELU>
__global__ __launch_bounds__(256, 2)
void gemm_bt(const unsigned short* __restrict__ A,
             const unsigned short* __restrict__ Bt,
             const float* __restrict__ bias,
             unsigned short* __restrict__ C,
             int M, int N, int K) {
    constexpr int BM = 128, BN = 128, BK = 64;
    __shared__ unsigned short As[BM * 64];
    __shared__ unsigned short Bs[BN * 64];
    const int e = blockIdx.z;
    const int gx = N / BN, gy = M / BM;
    const int nc = gx < 8 ? gx : 8;          // n-chunk width
    int id = blockIdx.x;
    const int per_chunk = nc * gy;
    const int chunk = id / per_chunk;
    const int r = id - chunk * per_chunk;
    const int bn = chunk * nc + (r % nc);
    const int bm = r / nc;

    const unsigned short* Ab = A  + (size_t)e * M * K + (size_t)bm * BM * K;
    const unsigned short* Bb = Bt + (size_t)e * N * K + (size_t)bn * BN * K;
    const float* bp = bias + (size_t)e * N;
    const int tid  = threadIdx.x;
    const int lane = tid & 63;
    const int wv   = tid >> 6;
    const int wm   = (wv >> 1) * 64;
    const int wn   = (wv & 1) * 64;
    const int lr   = lane & 15;
    const int quad = lane >> 4;
    const int srow   = lane >> 3;
    const int schunk = (lane & 7) ^ srow;
    const int swiz   = lr & 7;

    f32x4 acc[4][4] = {};

    for (int kb = 0; kb < K; kb += BK) {
        #pragma unroll
        for (int s = 0; s < 4; s++) {
            int q = wv * 4 + s;
            int row = q * 8 + srow;
            __builtin_amdgcn_global_load_lds(
                (const __attribute__((address_space(1))) unsigned int*)(Ab + (size_t)row * K + kb + schunk * 8),
                (__attribute__((address_space(3))) unsigned int*)(As + q * 512),
                16, 0, 0);
            __builtin_amdgcn_global_load_lds(
                (const __attribute__((address_space(1))) unsigned int*)(Bb + (size_t)row * K + kb + schunk * 8),
                (__attribute__((address_space(3))) unsigned int*)(Bs + q * 512),
                16, 0, 0);
        }
        __syncthreads();
        #pragma unroll
        for (int kk = 0; kk < BK; kk += 32) {
            bf16x8 af[4], bfr[4];
            const int sc = ((kk >> 3) + quad) ^ swiz;
            #pragma unroll
            for (int i = 0; i < 4; i++)
                af[i] = *reinterpret_cast<const bf16x8*>(&As[(wm + i*16 + lr) * 64 + sc * 8]);
            #pragma unroll
            for (int j = 0; j < 4; j++)
                bfr[j] = *reinterpret_cast<const bf16x8*>(&Bs[(wn + j*16 + lr) * 64 + sc * 8]);
            #pragma unroll
            for (int i = 0; i < 4; i++)
                #pragma unroll
                for (int j = 0; j < 4; j++)
                    acc[i][j] = __builtin_amdgcn_mfma_f32_16x16x32_bf16(af[i], bfr[j], acc[i][j], 0, 0, 0);
        }
        __syncthreads();
    }

    size_t cbase = (size_t)e * M * N + (size_t)bm * BM * N + (size_t)bn * BN;
    float bv[4];
    #pragma unroll
    for (int j = 0; j < 4; j++) bv[j] = bp[bn * BN + wn + j * 16 + lr];
    #pragma unroll
    for (int i = 0; i < 4; i++) {
        #pragma unroll
        for (int rr = 0; rr < 4; rr++) {
            int row = wm + i * 16 + quad * 4 + rr;
            #pragma unroll
            for (int j = 0; j < 4; j++) {
                int col = wn + j * 16 + lr;
                float v = acc[i][j][rr] + bv[j];
                if (GELU) v = 0.5f * v * (1.f + erff(v * 0.70710678118654752440f));
                C[cbase + (size_t)row * N + col] = f2bf(v);
            }
        }
    }
}

// ------------- combine: weighted sum of expert outputs, normalize -------------
__global__ void combine_kernel(const int* __restrict__ topi,
                               const float* __restrict__ topv,
                               const int* __restrict__ pos,
                               const unsigned short* __restrict__ out2,
                               float* __restrict__ y) {
    int t    = blockIdx.x * 4 + (threadIdx.x >> 6);
    int lane = threadIdx.x & 63;
    int e0 = topi[t*2],   e1 = topi[t*2+1];
    float g0 = topv[t*2], g1 = topv[t*2+1];
    int p0 = pos[t*2],    p1 = pos[t*2+1];
    float w0 = (p0 < CAP) ? g0 : 0.f;
    float w1 = (p1 < CAP) ? g1 : 0.f;
    float wsum = w0 + w1;
    float scale = (wsum > 0.f) ? 1.f / fmaxf(wsum, 1e-6f) : 0.f;
    int q0 = p0 < CAP ? p0 : CAP - 1;
    int q1 = p1 < CAP ? p1 : CAP - 1;
    const ushort4* o0 = reinterpret_cast<const ushort4*>(out2 + ((size_t)e0 * CAP + q0) * DMODEL);
    const ushort4* o1 = reinterpret_cast<const ushort4*>(out2 + ((size_t)e1 * CAP + q1) * DMODEL);
    float4* dst = reinterpret_cast<float4*>(y + (size_t)t * DMODEL);
    #pragma unroll
    for (int i = lane; i < DMODEL/4; i += 64) {
        ushort4 a = o0[i], b = o1[i];
        float4 r;
        r.x = (w0 * bf2f(a.x) + w1 * bf2f(b.x)) * scale;
        r.y = (w0 * bf2f(a.y) + w1 * bf2f(b.y)) * scale;
        r.z = (w0 * bf2f(a.z) + w1 * bf2f(b.z)) * scale;
        r.w = (w0 * bf2f(a.w) + w1 * bf2f(b.w)) * scale;
        dst[i] = r;
    }
}

extern "C" void kernel_launch(void* const* d_in, const int* in_sizes, int n_in,
                              void* d_out, int out_size, void* d_ws, size_t ws_size,
                              hipStream_t stream) {
    (void)in_sizes; (void)n_in; (void)out_size; (void)ws_size;
    const float* x        = (const float*)d_in[0];
    const float* w_router = (const float*)d_in[1];
    const float* b_router = (const float*)d_in[2];
    const float* w1       = (const float*)d_in[3];
    const float* b1       = (const float*)d_in[4];
    const float* w2       = (const float*)d_in[5];
    const float* b2       = (const float*)d_in[6];
    float* y = (float*)d_out;

    char* ws = (char*)d_ws;
    size_t off = 0;
    auto alloc = [&](size_t n) { char* p = ws + off; off = (off + n + 255) & ~(size_t)255; return p; };
    int*   topi     = (int*)  alloc((size_t)NASSIGN * 4);
    float* topv     = (float*)alloc((size_t)NASSIGN * 4);
    int*   pos      = (int*)  alloc((size_t)NASSIGN * 4);
    int*   slot_tok = (int*)  alloc((size_t)NEXP * CAP * 4);
    int*   kept     = (int*)  alloc(8 * 4);
    unsigned short* w1t = (unsigned short*)alloc((size_t)NEXP * DMODEL * FFF * 2);
    unsigned short* w2t = (unsigned short*)alloc((size_t)NEXP * DMODEL * FFF * 2);
    unsigned short* xb  = (unsigned short*)alloc((size_t)NEXP * CAP * DMODEL * 2);
    unsigned short* h   = (unsigned short*)alloc((size_t)NEXP * CAP * FFF * 2);
    unsigned short* out2 = w1t;  // alias: w1t is dead after GEMM1

    prologue_kernel<<<NTOK/4 + 4096, 256, 0, stream>>>(
        x, w_router, b_router, w1, w2, topi, topv, w1t, w2t);
    scan_kernel<<<1, 256, 0, stream>>>(topi, pos, slot_tok, kept);
    dispatch_kernel<<<NEXP*CAP/4, 256, 0, stream>>>(x, slot_tok, kept, xb);
    gemm_bt<1><<<dim3((FFF/128)*(CAP/128), 1, NEXP), 256, 0, stream>>>(xb, w1t, b1, h, CAP, FFF, DMODEL);
    gemm_bt<0><<<dim3((DMODEL/128)*(CAP/128), 1, NEXP), 256, 0, stream>>>(h, w2t, b2, out2, CAP, DMODEL, FFF);
    combine_kernel<<<NTOK/4, 256, 0, stream>>>(topi, topv, pos, out2, y);
}